// Round 5
// baseline (2493.527 us; speedup 1.0000x reference)
//
#include <hip/hip_runtime.h>
#include <hip/hip_cooperative_groups.h>
namespace cg = cooperative_groups;

#define TSTEPS 20
constexpr float THRES = 1.0f;
constexpr float DECAY = 0.875f;  // (2^3-1)/2^3

constexpr int DIM_IN = 64;
constexpr int NIN = DIM_IN * DIM_IN;          // 4096
constexpr int C1 = 64, K1 = 7, D1 = 58;
constexpr int N1 = C1 * D1 * D1;              // 215296
constexpr int C2 = 128, K2 = 7, D2 = 52;
constexpr int N2 = C2 * D2 * D2;              // 346112
constexpr int NFLAT = N2;
constexpr int NHID = 512;
constexpr int NOUT = 10;
constexpr int KC = 16;          // conv2 K-split chunks
constexpr int CPC = C1 / KC;    // 4 input channels per chunk
constexpr int W2R_ELEMS = 256 * 28 * 64;      // reshuffled conv2 weights

// persistent kernel geometry
constexpr int GRID = 1024;
constexpr int NB_GATHER = 512;                 // phase A: blocks [0,512) gather
constexpr int A_PART_END = 928;                // [512,928) partial, 928 misc
constexpr int NB_RED = N2 / 256;               // 1352 reduce tasks (phase B)
constexpr int BT_TASKS = NB_RED + C1 + 1;      // 1417

// fallback (round-4) geometry
constexpr int NB_PART = 832;
constexpr int NB1 = NB_GATHER + NB_PART + 1;   // 1345
constexpr int NB2 = NB_RED + C1 + 1;           // 1417

// Persistent state (zeroed every kernel_launch; harness doesn't re-poison).
__device__ float g_mp_in[NIN];
__device__ float g_s_in[NIN];
__device__ float g_mp_c1[N1];
__device__ float g_sp_c1[2][N1];   // double-buffered by step parity
__device__ float g_mp_c2[N2];
__device__ float g_sp_c2[N2];      // dense fallback path only
__device__ float g_mp_l1[NHID];
__device__ float g_sp_l1[NHID];
__device__ float g_mp_l2[NOUT];
__device__ float g_dot[NHID];      // linear1 dot accumulator
__device__ int   g_nnz[2];         // double-buffered spike counts
__device__ int   g_list[2][N2];    // double-buffered spike index lists

__global__ void init_kernel(float* __restrict__ out) {
    int i = blockIdx.x * blockDim.x + threadIdx.x;
    int stride = gridDim.x * blockDim.x;
    for (int j = i; j < NIN; j += stride) { g_mp_in[j] = 0.f; g_s_in[j] = 0.f; }
    for (int j = i; j < N1; j += stride) {
        g_mp_c1[j] = 0.f; g_sp_c1[0][j] = 0.f; g_sp_c1[1][j] = 0.f;
    }
    for (int j = i; j < N2; j += stride) { g_mp_c2[j] = 0.f; g_sp_c2[j] = 0.f; }
    if (i < NHID) { g_mp_l1[i] = 0.f; g_sp_l1[i] = 0.f; g_dot[i] = 0.f; }
    if (i < NOUT) g_mp_l2[i] = 0.f;
    if (i < (TSTEPS + 1) * NOUT) out[i] = 0.f;
    if (i < 2) g_nnz[i] = 0;
}

// One-time: w_l1 [512][NFLAT] -> wT [NFLAT][512]. 64x64 tiles.
__global__ void __launch_bounds__(256) transpose_kernel(const float* __restrict__ w,
                                                        float* __restrict__ wT) {
    __shared__ float tile[64][65];
    int bx = blockIdx.x * 64;
    int by = blockIdx.y * 64;
    int tx = threadIdx.x & 63, ty = threadIdx.x >> 6;
#pragma unroll
    for (int k = 0; k < 16; ++k)
        tile[ty + 4 * k][tx] = w[(size_t)(by + ty + 4 * k) * NFLAT + bx + tx];
    __syncthreads();
#pragma unroll
    for (int k = 0; k < 16; ++k)
        wT[(size_t)(bx + ty + 4 * k) * NHID + by + tx] = tile[tx][ty + 4 * k];
}

// One-time: w_c2 [co][ci][ky][kx] -> w2r [(kc*16+cot)][c*7+ky][cl*8+kx] (kx pad 8)
__global__ void __launch_bounds__(256) reshuffle_w2(const float* __restrict__ w2,
                                                    float* __restrict__ w2r) {
    int idx = blockIdx.x * 256 + threadIdx.x;
    if (idx >= C2 * C1 * 49) return;
    int co = idx / (C1 * 49);
    int rem = idx - co * (C1 * 49);
    int ci = rem / 49;
    int k = rem - ci * 49;
    int ky = k / 7, kx = k - ky * 7;
    int kc = ci >> 2, c = ci & 3;
    int cot = co >> 3, cl = co & 7;
    w2r[((size_t)(kc * 16 + cot) * 28 + (c * 7 + ky)) * 64 + cl * 8 + kx] = w2[idx];
}

// ============ persistent cooperative kernel: all 20 steps ============
// Live ranges: input 0..16, conv1 1..16, conv2 2..17, l1 3..18, l2 4..19.
__global__ void __launch_bounds__(256, 4) persist(
    const float* __restrict__ w1,
    const float* __restrict__ w2r,
    const float* __restrict__ wT,
    const float* __restrict__ wl2,
    const float* __restrict__ image,
    float* __restrict__ part,
    float* __restrict__ out) {
    __shared__ union __align__(16) {
        struct { float spk[CPC][10][58]; float wts[4][28][64]; } pa;  // 37.95 KB
        float sim[NIN];                                                // 16 KB
    } sm;
    cg::grid_group grid = cg::this_grid();
    int bid = blockIdx.x, tid = threadIdx.x;
    int wid = tid >> 6, lane = tid & 63;

    for (int t = 0; t < TSTEPS; ++t) {
        // ---------------- phase A: gather || conv2-partial || misc ----------------
        if (bid < NB_GATHER) {
            if (t >= 3 && t <= 18) {
                int p = (t + 1) & 1;               // parity of step t-1
                int nnz = g_nnz[p];
                const int* __restrict__ list = g_list[p];
                const float2* __restrict__ wT2 = (const float2*)wT;
                int h = tid;
                float2 a0 = {0.f,0.f}, a1 = {0.f,0.f}, a2 = {0.f,0.f}, a3 = {0.f,0.f};
                int i = bid;
                for (; i + 3 * NB_GATHER < nnz; i += 4 * NB_GATHER) {
                    int j0 = list[i];
                    int j1 = list[i + NB_GATHER];
                    int j2 = list[i + 2 * NB_GATHER];
                    int j3 = list[i + 3 * NB_GATHER];
                    float2 w0 = wT2[(size_t)j0 * 256 + h];
                    float2 w1v = wT2[(size_t)j1 * 256 + h];
                    float2 w2v = wT2[(size_t)j2 * 256 + h];
                    float2 w3 = wT2[(size_t)j3 * 256 + h];
                    a0.x += w0.x; a0.y += w0.y;
                    a1.x += w1v.x; a1.y += w1v.y;
                    a2.x += w2v.x; a2.y += w2v.y;
                    a3.x += w3.x; a3.y += w3.y;
                }
                for (; i < nnz; i += NB_GATHER) {
                    float2 w0 = wT2[(size_t)list[i] * 256 + h];
                    a0.x += w0.x; a0.y += w0.y;
                }
                atomicAdd(&g_dot[2 * h], a0.x + a1.x + a2.x + a3.x);
                atomicAdd(&g_dot[2 * h + 1], a0.y + a1.y + a2.y + a3.y);
            }
        } else if (bid < A_PART_END) {
            if (t >= 2 && t <= 17) {
                int pb = bid - NB_GATHER;          // 0..415
                int task0 = pb * 2;                // both tasks share (kc,yt)
                int kcyt = task0 >> 2;
                int kc = kcyt / 13, yt = kcyt - kc * 13;
                int c0 = kc * CPC, y0 = yt * 4;
                const float* __restrict__ sp = g_sp_c1[(t + 1) & 1];
                // stage spike tile once per block (shared by 4 waves, 2 tasks)
                for (int e = tid; e < CPC * 10 * 58; e += 256) {
                    int c = e / 580, rem = e - c * 580;
                    int r = rem / 58, x = rem - r * 58;
                    sm.pa.spk[c][r][x] = sp[(c0 + c) * (D1 * D1) + (y0 + r) * D1 + x];
                }
                __syncthreads();
                bool act = lane < D2;
#pragma unroll 1
                for (int s = 0; s < 2; ++s) {
                    int cotG = (task0 + s) & 3;
                    int cot = cotG * 4 + wid;
                    int co0 = cot * 8;
                    // stage this wave's weight slice (contiguous 7.2 KB)
                    const float4* __restrict__ wsrc =
                        (const float4*)(w2r + (size_t)(kc * 16 + cot) * 1792);
                    float4* wdst = (float4*)&sm.pa.wts[wid][0][0];
#pragma unroll
                    for (int j = 0; j < 7; ++j)
                        wdst[j * 64 + lane] = wsrc[j * 64 + lane];
                    float acc[8][4] = {};
#pragma unroll 1
                    for (int c = 0; c < CPC; ++c) {
#pragma unroll
                        for (int ky = 0; ky < K2; ++ky) {
                            float v[4][8];
                            if (act) {
#pragma unroll
                                for (int o = 0; o < 4; ++o)
#pragma unroll
                                    for (int k = 0; k < 8; ++k)
                                        v[o][k] = sm.pa.spk[c][o + ky][lane + k];
                            }
#pragma unroll
                            for (int cl = 0; cl < 8; ++cl) {
                                float w8[8];
#pragma unroll
                                for (int k = 0; k < 8; ++k)
                                    w8[k] = sm.pa.wts[wid][c * 7 + ky][cl * 8 + k];
                                if (act) {
#pragma unroll
                                    for (int o = 0; o < 4; ++o)
#pragma unroll
                                        for (int kx = 0; kx < 7; ++kx)
                                            acc[cl][o] = fmaf(v[o][kx], w8[kx], acc[cl][o]);
                                }
                            }
                        }
                    }
                    if (act) {
#pragma unroll
                        for (int cl = 0; cl < 8; ++cl)
#pragma unroll
                            for (int o = 0; o < 4; ++o)
                                part[(size_t)kc * N2 + (co0 + cl) * (D2 * D2) +
                                     (y0 + o) * D2 + lane] = acc[cl][o];
                    }
                }
            }
        } else if (bid == A_PART_END) {
            // misc: nnz reset, input integrate/fire, linear2
            if (tid == 0) g_nnz[t & 1] = 0;
            if (t <= 16) {
                for (int j = tid; j < NIN; j += 256) {
                    float mp = g_mp_in[j] + image[j];
                    float f = (mp >= THRES) ? 1.f : 0.f;
                    g_s_in[j] = f;
                    g_mp_in[j] = mp - THRES * f;   // SnnInput: no decay
                }
            }
            if (t >= 4) {
                for (int o = wid; o < NOUT; o += 4) {
                    float a = 0.f;
#pragma unroll
                    for (int k = lane; k < NHID; k += 64)
                        a = fmaf(wl2[o * NHID + k], g_sp_l1[k], a);
                    for (int off = 32; off; off >>= 1) a += __shfl_down(a, off, 64);
                    if (lane == 0) {
                        float mp = g_mp_l2[o] * DECAY + a;
                        float f = (mp >= THRES) ? 1.f : 0.f;
                        g_mp_l2[o] = mp - THRES * f;
                        out[(t + 1) * NOUT + o] = f;
                    }
                }
            }
        }
        __threadfence();
        grid.sync();
        // ---------------- phase B: reduce || conv1 || l1-finish ----------------
        for (int task = bid; task < BT_TASKS; task += GRID) {
            if (task < NB_RED) {
                if (t >= 2 && t <= 17) {
                    int i = task * 256 + tid;
                    float s = 0.f;
#pragma unroll
                    for (int k = 0; k < KC; ++k) s += part[(size_t)k * N2 + i];
                    float mp = g_mp_c2[i] + s;
                    float f = (mp >= THRES) ? 1.f : 0.f;
                    g_mp_c2[i] = (mp - THRES * f) * ((f > 0.f) ? 1.f : DECAY);
                    if (f > 0.f) {
                        int pos = atomicAdd(&g_nnz[t & 1], 1);
                        g_list[t & 1][pos] = i;
                    }
                }
            } else if (task < NB_RED + C1) {
                if (t >= 1 && t <= 16) {
                    int co = task - NB_RED;
                    const float4* __restrict__ s4 = (const float4*)g_s_in;
                    float4* d4 = (float4*)sm.sim;
                    for (int j = tid; j < NIN / 4; j += 256) d4[j] = s4[j];
                    __syncthreads();
                    float w[49];
#pragma unroll
                    for (int k = 0; k < 49; ++k) w[k] = w1[co * 49 + k];
                    float* __restrict__ spb = g_sp_c1[t & 1];
                    for (int idx = tid; idx < D1 * D1; idx += 256) {
                        int y = idx / D1, x = idx - y * D1;
                        float a = 0.f;
#pragma unroll
                        for (int ky = 0; ky < K1; ++ky)
#pragma unroll
                            for (int kx = 0; kx < K1; ++kx)
                                a = fmaf(sm.sim[(y + ky) * DIM_IN + x + kx],
                                         w[ky * K1 + kx], a);
                        int o = co * (D1 * D1) + idx;
                        float mp = g_mp_c1[o] + a;
                        float f = (mp >= THRES) ? 1.f : 0.f;
                        g_mp_c1[o] = (mp - THRES * f) * ((f > 0.f) ? 1.f : DECAY);
                        spb[o] = f;
                    }
                    __syncthreads();  // sim reuse safety across task loop
                }
            } else {
                if (t >= 3 && t <= 18) {
                    for (int i = tid; i < NHID; i += 256) {
                        float mp = g_mp_l1[i] * DECAY + g_dot[i];
                        float f = (mp >= THRES) ? 1.f : 0.f;
                        g_mp_l1[i] = mp - THRES * f;
                        g_sp_l1[i] = f;
                        g_dot[i] = 0.f;
                    }
                }
            }
        }
        __threadfence();
        grid.sync();
    }
}

// ================== round-4 fallback path (proven) ==================
__global__ void __launch_bounds__(256) mega1(const float* __restrict__ w2,
                                             const float* __restrict__ wT,
                                             const float* __restrict__ wl2,
                                             const float* __restrict__ image,
                                             float* __restrict__ part,
                                             float* __restrict__ out,
                                             int t, int sparse) {
    __shared__ float ssp[4][CPC][10][58];
    int bid = blockIdx.x, tid = threadIdx.x;
    if (bid < NB_GATHER) {
        if (!sparse || t < 3 || t > 18) return;
        int p = (t + 1) & 1;
        int nnz = g_nnz[p];
        const int* __restrict__ list = g_list[p];
        const float2* __restrict__ wT2 = (const float2*)wT;
        int h = tid;
        float2 a0 = {0.f,0.f}, a1 = {0.f,0.f}, a2 = {0.f,0.f}, a3 = {0.f,0.f};
        int i = bid;
        for (; i + 3 * NB_GATHER < nnz; i += 4 * NB_GATHER) {
            int j0 = list[i];
            int j1 = list[i + NB_GATHER];
            int j2 = list[i + 2 * NB_GATHER];
            int j3 = list[i + 3 * NB_GATHER];
            float2 w0 = wT2[(size_t)j0 * 256 + h];
            float2 w1 = wT2[(size_t)j1 * 256 + h];
            float2 w2v = wT2[(size_t)j2 * 256 + h];
            float2 w3 = wT2[(size_t)j3 * 256 + h];
            a0.x += w0.x; a0.y += w0.y;
            a1.x += w1.x; a1.y += w1.y;
            a2.x += w2v.x; a2.y += w2v.y;
            a3.x += w3.x; a3.y += w3.y;
        }
        for (; i < nnz; i += NB_GATHER) {
            float2 w0 = wT2[(size_t)list[i] * 256 + h];
            a0.x += w0.x; a0.y += w0.y;
        }
        atomicAdd(&g_dot[2 * h], a0.x + a1.x + a2.x + a3.x);
        atomicAdd(&g_dot[2 * h + 1], a0.y + a1.y + a2.y + a3.y);
    } else if (bid < NB_GATHER + NB_PART) {
        if (t < 2 || t > 17) return;
        int wid = tid >> 6, lane = tid & 63;
        int wt = __builtin_amdgcn_readfirstlane((bid - NB_GATHER) * 4 + wid);
        int kc = wt & 15;
        int cot = (wt >> 4) & 15;
        int yt = wt >> 8;
        int co0 = cot * 8, y0 = yt * 4, c0 = kc * CPC;
        const float* __restrict__ sp = g_sp_c1[(t + 1) & 1];
        for (int e = lane; e < CPC * 10 * 58; e += 64) {
            int c = e / 580;
            int rem = e - c * 580;
            int r = rem / 58, x = rem - r * 58;
            ssp[wid][c][r][x] = sp[(c0 + c) * (D1 * D1) + (y0 + r) * D1 + x];
        }
        float acc[8][4] = {};
        bool act = lane < D2;
#pragma unroll 1
        for (int c = 0; c < CPC; ++c) {
#pragma unroll
            for (int ky = 0; ky < K2; ++ky) {
                float wv[8][7];
#pragma unroll
                for (int cl = 0; cl < 8; ++cl)
#pragma unroll
                    for (int kx = 0; kx < 7; ++kx)
                        wv[cl][kx] = w2[((size_t)(co0 + cl) * C1 + c0 + c) * 49 + ky * 7 + kx];
                if (act) {
#pragma unroll
                    for (int o = 0; o < 4; ++o) {
                        float v[7];
#pragma unroll
                        for (int kx = 0; kx < 7; ++kx) v[kx] = ssp[wid][c][o + ky][lane + kx];
#pragma unroll
                        for (int kx = 0; kx < 7; ++kx)
#pragma unroll
                            for (int cl = 0; cl < 8; ++cl)
                                acc[cl][o] = fmaf(v[kx], wv[cl][kx], acc[cl][o]);
                    }
                }
            }
        }
        if (act) {
#pragma unroll
            for (int cl = 0; cl < 8; ++cl)
#pragma unroll
                for (int o = 0; o < 4; ++o)
                    part[(size_t)kc * N2 + (co0 + cl) * (D2 * D2) + (y0 + o) * D2 + lane] =
                        acc[cl][o];
        }
    } else {
        if (tid == 0) g_nnz[t & 1] = 0;
        if (t <= 16) {
            for (int j = tid; j < NIN; j += 256) {
                float mp = g_mp_in[j] + image[j];
                float f = (mp >= THRES) ? 1.f : 0.f;
                g_s_in[j] = f;
                g_mp_in[j] = mp - THRES * f;
            }
        }
        if (t >= 4) {
            int w = tid >> 6, lane = tid & 63;
            for (int o = w; o < NOUT; o += 4) {
                float a = 0.f;
#pragma unroll
                for (int k = lane; k < NHID; k += 64)
                    a = fmaf(wl2[o * NHID + k], g_sp_l1[k], a);
                for (int off = 32; off; off >>= 1) a += __shfl_down(a, off, 64);
                if (lane == 0) {
                    float mp = g_mp_l2[o] * DECAY + a;
                    float f = (mp >= THRES) ? 1.f : 0.f;
                    g_mp_l2[o] = mp - THRES * f;
                    out[(t + 1) * NOUT + o] = f;
                }
            }
        }
    }
}

__global__ void __launch_bounds__(256) mega2(const float* __restrict__ w1,
                                             const float* __restrict__ part,
                                             int t) {
    __shared__ float sim[NIN];
    int bid = blockIdx.x, tid = threadIdx.x;
    if (bid < NB_RED) {
        if (t < 2 || t > 17) return;
        int i = bid * 256 + tid;
        float s = 0.f;
#pragma unroll
        for (int k = 0; k < KC; ++k) s += part[(size_t)k * N2 + i];
        float mp = g_mp_c2[i] + s;
        float f = (mp >= THRES) ? 1.f : 0.f;
        g_mp_c2[i] = (mp - THRES * f) * ((f > 0.f) ? 1.f : DECAY);
        g_sp_c2[i] = f;
        if (f > 0.f) {
            int pos = atomicAdd(&g_nnz[t & 1], 1);
            g_list[t & 1][pos] = i;
        }
    } else if (bid < NB_RED + C1) {
        if (t < 1 || t > 16) return;
        int co = bid - NB_RED;
        const float4* __restrict__ s4 = (const float4*)g_s_in;
        float4* d4 = (float4*)sim;
        for (int j = tid; j < NIN / 4; j += 256) d4[j] = s4[j];
        __syncthreads();
        float w[49];
#pragma unroll
        for (int k = 0; k < 49; ++k) w[k] = w1[co * 49 + k];
        float* __restrict__ spb = g_sp_c1[t & 1];
        for (int idx = tid; idx < D1 * D1; idx += 256) {
            int y = idx / D1, x = idx - y * D1;
            float a = 0.f;
#pragma unroll
            for (int ky = 0; ky < K1; ++ky)
#pragma unroll
                for (int kx = 0; kx < K1; ++kx)
                    a = fmaf(sim[(y + ky) * DIM_IN + x + kx], w[ky * K1 + kx], a);
            int o = co * (D1 * D1) + idx;
            float mp = g_mp_c1[o] + a;
            float f = (mp >= THRES) ? 1.f : 0.f;
            g_mp_c1[o] = (mp - THRES * f) * ((f > 0.f) ? 1.f : DECAY);
            spb[o] = f;
        }
    } else {
        if (t < 3 || t > 18) return;
        for (int i = tid; i < NHID; i += 256) {
            float mp = g_mp_l1[i] * DECAY + g_dot[i];
            float f = (mp >= THRES) ? 1.f : 0.f;
            g_mp_l1[i] = mp - THRES * f;
            g_sp_l1[i] = f;
            g_dot[i] = 0.f;
        }
    }
}

__global__ void __launch_bounds__(256) linear1_dense(const float* __restrict__ wl1) {
    int row = blockIdx.x;
    const float4* __restrict__ w4 = (const float4*)(wl1 + (size_t)row * NFLAT);
    const float4* __restrict__ s4 = (const float4*)g_sp_c2;
    float acc = 0.f;
    for (int j = threadIdx.x; j < NFLAT / 4; j += 256) {
        float4 w = w4[j];
        float4 s = s4[j];
        acc += w.x * s.x + w.y * s.y + w.z * s.z + w.w * s.w;
    }
    __shared__ float red[256];
    red[threadIdx.x] = acc;
    __syncthreads();
    for (int off = 128; off >= 1; off >>= 1) {
        if (threadIdx.x < off) red[threadIdx.x] += red[threadIdx.x + off];
        __syncthreads();
    }
    if (threadIdx.x == 0) g_dot[row] = red[0];
}

extern "C" void kernel_launch(void* const* d_in, const int* in_sizes, int n_in,
                              void* d_out, int out_size, void* d_ws, size_t ws_size,
                              hipStream_t stream) {
    const float* image = (const float*)d_in[0];
    const float* w_c1 = (const float*)d_in[1];
    const float* w_c2 = (const float*)d_in[2];
    const float* w_l1 = (const float*)d_in[3];
    const float* w_l2 = (const float*)d_in[4];
    float* out = (float*)d_out;

    float* wT = (float*)d_ws;
    size_t wt_elems = (size_t)NFLAT * NHID;
    size_t part_elems = (size_t)KC * N2;
    bool sparse = ws_size >= (wt_elems + part_elems + W2R_ELEMS) * sizeof(float);
    float* part = sparse ? wT + wt_elems : (float*)d_ws;
    float* w2r = sparse ? part + part_elems : (float*)d_ws;

    init_kernel<<<512, 256, 0, stream>>>(out);
    if (sparse) {
        transpose_kernel<<<dim3(NFLAT / 64, NHID / 64), 256, 0, stream>>>(w_l1, wT);
        reshuffle_w2<<<(C2 * C1 * 49 + 255) / 256, 256, 0, stream>>>(w_c2, w2r);
    }

    bool coop = false;
    if (sparse) {
        int maxB = 0;
        if (hipOccupancyMaxActiveBlocksPerMultiprocessor(&maxB, persist, 256, 0) ==
                hipSuccess && maxB >= 4) {
            const float* a0 = w_c1; const float* a1 = w2r; const float* a2 = wT;
            const float* a3 = w_l2; const float* a4 = image;
            float* a5 = part; float* a6 = out;
            void* args[] = {(void*)&a0, (void*)&a1, (void*)&a2, (void*)&a3,
                            (void*)&a4, (void*)&a5, (void*)&a6};
            hipError_t e = hipLaunchCooperativeKernel((const void*)persist, dim3(GRID),
                                                      dim3(256), args, 0, stream);
            if (e == hipSuccess) coop = true;
            else (void)hipGetLastError();
        }
    }
    if (!coop) {
        for (int t = 0; t < TSTEPS; ++t) {
            if (!sparse && t >= 3 && t <= 18)
                linear1_dense<<<NHID, 256, 0, stream>>>(w_l1);
            mega1<<<NB1, 256, 0, stream>>>(w_c2, wT, w_l2, image, part, out, t,
                                           sparse ? 1 : 0);
            if (t >= 1 && t <= 18)
                mega2<<<NB2, 256, 0, stream>>>(w_c1, part, t);
        }
    }
}